// Round 1
// baseline (220.241 us; speedup 1.0000x reference)
//
#include <hip/hip_runtime.h>
#include <math.h>

namespace {

constexpr int NB = 64, NT = 16384;
constexpr int NBT = NB * NT;              // 1,048,576 (b,t) pairs, 4 sources each
constexpr int NBLK   = 2048;              // blocks in main kernel
constexpr int NTHR   = 256;
constexpr int NPASS  = NBT / (NBLK * NTHR);   // 2 pairs per thread
constexpr float VAD_TH  = 2.0f / 3.0f;
constexpr float AE_TH   = 30.0f;
constexpr float D2R     = 0.017453292519943295f;
constexpr float R2D     = 57.29577951308232f;
constexpr float CLIPV   = 0.99999f;

// ws layout: float part[5][NBLK] (SoA, 40 KB) followed by one u32 arrival counter.
// metrics: 0=act 1=corr 2=ele 3=azi 4=aziele

typedef float f32x4 __attribute__((ext_vector_type(4)));

// Non-temporal 16B load: every input byte is read exactly once and the harness's
// 256 MiB poison-fill has just flushed L2/L3 — caching the stream is pure overhead.
__device__ __forceinline__ f32x4 ntld(const f32x4* __restrict__ p) {
    return __builtin_nontemporal_load(p);
}

__device__ __forceinline__ void process4(
    const f32x4 eg, const f32x4 ag, const f32x4 ee, const f32x4 ae,
    const f32x4 vg4, const f32x4 ve4,
    float& act, float& corr, float& s_ele, float& s_azi, float& s_ae)
{
#pragma unroll
    for (int s = 0; s < 4; ++s) {
        float vg = (vg4[s] > VAD_TH) ? 1.f : 0.f;
        float ve = (ve4[s] > VAD_TH) ? vg : 0.f;

        // floor-mod(d,360) for d in [-180,540]; bit-identical to numpy's
        // fmod-then-adjust (Sterbenz for the subtract branch).
        float d = ae[s] - ag[s] + 180.f;
        d = (d < 0.f) ? d + 360.f : d;
        d = (d >= 360.f) ? d - 360.f : d;
        float azi_err = fabsf(d - 180.f);

        float ele_err = fabsf(ee[s] - eg[s]);

        float gr = eg[s] * D2R;
        float er = ee[s] * D2R;
        float ar = ag[s] * D2R - ae[s] * D2R;
        float aux = __cosf(gr) * __cosf(er) + __sinf(gr) * __sinf(er) * __cosf(ar);
        aux = fminf(fmaxf(aux, -CLIPV), CLIPV);
        float ae_err = acosf(aux) * R2D;     // acos >= 0

        act += vg;
        if (azi_err < AE_TH) corr += ve;
        s_ele += vg * ele_err;
        s_azi += vg * azi_err;
        s_ae  += vg * ae_err;
    }
}

__global__ __launch_bounds__(NTHR) void metric_main(
    const float* __restrict__ doa_gt, const float* __restrict__ vad_gt,
    const float* __restrict__ doa_est, const float* __restrict__ vad_est,
    float* __restrict__ part, unsigned* __restrict__ cnt,
    float* __restrict__ out)
{
    const int gid = blockIdx.x * NTHR + threadIdx.x;

    const f32x4* dg = reinterpret_cast<const f32x4*>(doa_gt);
    const f32x4* de = reinterpret_cast<const f32x4*>(doa_est);
    const f32x4* vg_p = reinterpret_cast<const f32x4*>(vad_gt);
    const f32x4* ve_p = reinterpret_cast<const f32x4*>(vad_est);

    // Issue ALL loads before any compute: 12 outstanding float4 loads/thread
    // (memory-level parallelism — evidence showed the loop is latency-bound
    // when passes serialize their loads).
    const int i0 = gid;                       // pass 0, coalesced
    const int i1 = gid + NBLK * NTHR;         // pass 1, coalesced
    static_assert(NPASS == 2, "load schedule assumes 2 passes");

    f32x4 eg0 = ntld(&dg[2 * i0]), ag0 = ntld(&dg[2 * i0 + 1]);
    f32x4 ee0 = ntld(&de[2 * i0]), ae0 = ntld(&de[2 * i0 + 1]);
    f32x4 eg1 = ntld(&dg[2 * i1]), ag1 = ntld(&dg[2 * i1 + 1]);
    f32x4 ee1 = ntld(&de[2 * i1]), ae1 = ntld(&de[2 * i1 + 1]);
    f32x4 vg40 = ntld(&vg_p[i0]), ve40 = ntld(&ve_p[i0]);
    f32x4 vg41 = ntld(&vg_p[i1]), ve41 = ntld(&ve_p[i1]);

    float act = 0.f, corr = 0.f, s_ele = 0.f, s_azi = 0.f, s_ae = 0.f;
    process4(eg0, ag0, ee0, ae0, vg40, ve40, act, corr, s_ele, s_azi, s_ae);
    process4(eg1, ag1, ee1, ae1, vg41, ve41, act, corr, s_ele, s_azi, s_ae);

    // wave64 shuffle reduction
#pragma unroll
    for (int off = 32; off > 0; off >>= 1) {
        act   += __shfl_down(act,   off, 64);
        corr  += __shfl_down(corr,  off, 64);
        s_ele += __shfl_down(s_ele, off, 64);
        s_azi += __shfl_down(s_azi, off, 64);
        s_ae  += __shfl_down(s_ae,  off, 64);
    }

    __shared__ float sm[4][5];
    __shared__ int   sm_last;
    __shared__ double dsm[4][5];

    const int wave = threadIdx.x >> 6;
    const int lane = threadIdx.x & 63;
    if (lane == 0) {
        sm[wave][0] = act;  sm[wave][1] = corr; sm[wave][2] = s_ele;
        sm[wave][3] = s_azi; sm[wave][4] = s_ae;
    }
    __syncthreads();
    if (threadIdx.x == 0) {
        part[0 * NBLK + blockIdx.x] = sm[0][0] + sm[1][0] + sm[2][0] + sm[3][0];
        part[1 * NBLK + blockIdx.x] = sm[0][1] + sm[1][1] + sm[2][1] + sm[3][1];
        part[2 * NBLK + blockIdx.x] = sm[0][2] + sm[1][2] + sm[2][2] + sm[3][2];
        part[3 * NBLK + blockIdx.x] = sm[0][3] + sm[1][3] + sm[2][3] + sm[3][3];
        part[4 * NBLK + blockIdx.x] = sm[0][4] + sm[1][4] + sm[2][4] + sm[3][4];
        // release: make partials visible device-wide before signalling arrival
        __threadfence();
        unsigned old = atomicAdd(cnt, 1u);
        sm_last = (old == (unsigned)(NBLK - 1)) ? 1 : 0;
    }
    __syncthreads();
    if (!sm_last) return;

    // ---- last-arriving block: finalize (identical order/precision to the old
    // metric_finalize kernel → bit-identical outputs) ----
    __threadfence();   // acquire: see every block's partials
    const int t = threadIdx.x;
    double v[5];
#pragma unroll
    for (int m = 0; m < 5; ++m) {
        double acc = 0.0;
#pragma unroll
        for (int j = 0; j < NBLK / NTHR; ++j)
            acc += (double)part[m * NBLK + j * NTHR + t];
        v[m] = acc;
    }
#pragma unroll
    for (int off = 32; off > 0; off >>= 1)
#pragma unroll
        for (int m = 0; m < 5; ++m)
            v[m] += __shfl_down(v[m], off, 64);

    if (lane == 0)
#pragma unroll
        for (int m = 0; m < 5; ++m) dsm[wave][m] = v[m];
    __syncthreads();
    if (t == 0) {
        double tot[5];
#pragma unroll
        for (int m = 0; m < 5; ++m)
            tot[m] = dsm[0][m] + dsm[1][m] + dsm[2][m] + dsm[3][m];
        double act_s = tot[0];
        out[0] = (float)(tot[1] / act_s);   // ACC
        out[1] = (float)(tot[2] / act_s);   // MAE ele
        out[2] = (float)(tot[3] / act_s);   // MAE azi
        out[3] = (float)(tot[4] / act_s);   // MAE aziele
    }
}

} // namespace

extern "C" void kernel_launch(void* const* d_in, const int* in_sizes, int n_in,
                              void* d_out, int out_size, void* d_ws, size_t ws_size,
                              hipStream_t stream) {
    const float* doa_gt  = (const float*)d_in[0];
    const float* vad_gt  = (const float*)d_in[1];
    const float* doa_est = (const float*)d_in[2];
    const float* vad_est = (const float*)d_in[3];
    float* part = (float*)d_ws;                                  // 5 * NBLK floats = 40 KB
    unsigned* cnt = (unsigned*)((char*)d_ws + 5 * NBLK * sizeof(float));
    float* out  = (float*)d_out;

    // Arrival counter must be 0 at every launch (graph replays included) —
    // a 4-byte memset node is graph-capturable and ~free.
    hipMemsetAsync(cnt, 0, sizeof(unsigned), stream);
    metric_main<<<NBLK, NTHR, 0, stream>>>(doa_gt, vad_gt, doa_est, vad_est, part, cnt, out);
}

// Round 2
// 212.009 us; speedup vs baseline: 1.0388x; 1.0388x over previous
//
#include <hip/hip_runtime.h>
#include <math.h>

namespace {

constexpr int NB = 64, NT = 16384;
constexpr int NBT = NB * NT;              // 1,048,576 (b,t) pairs, 4 sources each
constexpr int NBLK   = 2048;              // blocks in main kernel
constexpr int NTHR   = 256;
constexpr int NPASS  = NBT / (NBLK * NTHR);   // 2 pairs per thread
constexpr float VAD_TH  = 2.0f / 3.0f;
constexpr float AE_TH   = 30.0f;
constexpr float D2R     = 0.017453292519943295f;
constexpr float R2D     = 57.29577951308232f;
constexpr float CLIPV   = 0.99999f;

// ws layout: float part[5][NBLK] (SoA, 40 KB) followed by one u32 arrival counter.
// metrics: 0=act 1=corr 2=ele 3=azi 4=aziele
//
// NOTE (round-1 post-mortem): do NOT use __builtin_nontemporal_load here.
// The nt path bypasses L2/L3; inputs (96 MiB) fit in the 256 MiB Infinity
// Cache and FETCH_SIZE showed ~50% of reads are L3-served with plain loads.
// nt loads measured 121 µs / 438 GB/s vs <40 µs with cached loads.

__device__ __forceinline__ void process4(
    const float4& eg, const float4& ag, const float4& ee, const float4& ae,
    const float4& vg4, const float4& ve4,
    float& act, float& corr, float& s_ele, float& s_azi, float& s_ae)
{
    float egA[4] = {eg.x, eg.y, eg.z, eg.w}, agA[4] = {ag.x, ag.y, ag.z, ag.w};
    float eeA[4] = {ee.x, ee.y, ee.z, ee.w}, aeA[4] = {ae.x, ae.y, ae.z, ae.w};
    float vgA[4] = {vg4.x, vg4.y, vg4.z, vg4.w}, veA[4] = {ve4.x, ve4.y, ve4.z, ve4.w};

#pragma unroll
    for (int s = 0; s < 4; ++s) {
        float vg = (vgA[s] > VAD_TH) ? 1.f : 0.f;
        float ve = (veA[s] > VAD_TH) ? vg : 0.f;

        // floor-mod(d,360) for d in [-180,540]; bit-identical to numpy's
        // fmod-then-adjust (Sterbenz for the subtract branch).
        float d = aeA[s] - agA[s] + 180.f;
        d = (d < 0.f) ? d + 360.f : d;
        d = (d >= 360.f) ? d - 360.f : d;
        float azi_err = fabsf(d - 180.f);

        float ele_err = fabsf(eeA[s] - egA[s]);

        float gr = egA[s] * D2R;
        float er = eeA[s] * D2R;
        float ar = agA[s] * D2R - aeA[s] * D2R;
        float aux = __cosf(gr) * __cosf(er) + __sinf(gr) * __sinf(er) * __cosf(ar);
        aux = fminf(fmaxf(aux, -CLIPV), CLIPV);
        float ae_err = acosf(aux) * R2D;     // acos >= 0

        act += vg;
        if (azi_err < AE_TH) corr += ve;
        s_ele += vg * ele_err;
        s_azi += vg * azi_err;
        s_ae  += vg * ae_err;
    }
}

__global__ __launch_bounds__(NTHR) void metric_main(
    const float* __restrict__ doa_gt, const float* __restrict__ vad_gt,
    const float* __restrict__ doa_est, const float* __restrict__ vad_est,
    float* __restrict__ part, unsigned* __restrict__ cnt,
    float* __restrict__ out)
{
    const int gid = blockIdx.x * NTHR + threadIdx.x;

    const float4* dg = reinterpret_cast<const float4*>(doa_gt);
    const float4* de = reinterpret_cast<const float4*>(doa_est);
    const float4* vg_p = reinterpret_cast<const float4*>(vad_gt);
    const float4* ve_p = reinterpret_cast<const float4*>(vad_est);

    // Issue ALL loads before any compute: 12 outstanding float4 loads/thread
    // (memory-level parallelism — the loop is latency-bound when passes
    // serialize their loads).
    const int i0 = gid;                       // pass 0, coalesced
    const int i1 = gid + NBLK * NTHR;         // pass 1, coalesced
    static_assert(NPASS == 2, "load schedule assumes 2 passes");

    float4 eg0 = dg[2 * i0], ag0 = dg[2 * i0 + 1];
    float4 ee0 = de[2 * i0], ae0 = de[2 * i0 + 1];
    float4 eg1 = dg[2 * i1], ag1 = dg[2 * i1 + 1];
    float4 ee1 = de[2 * i1], ae1 = de[2 * i1 + 1];
    float4 vg40 = vg_p[i0], ve40 = ve_p[i0];
    float4 vg41 = vg_p[i1], ve41 = ve_p[i1];

    float act = 0.f, corr = 0.f, s_ele = 0.f, s_azi = 0.f, s_ae = 0.f;
    process4(eg0, ag0, ee0, ae0, vg40, ve40, act, corr, s_ele, s_azi, s_ae);
    process4(eg1, ag1, ee1, ae1, vg41, ve41, act, corr, s_ele, s_azi, s_ae);

    // wave64 shuffle reduction
#pragma unroll
    for (int off = 32; off > 0; off >>= 1) {
        act   += __shfl_down(act,   off, 64);
        corr  += __shfl_down(corr,  off, 64);
        s_ele += __shfl_down(s_ele, off, 64);
        s_azi += __shfl_down(s_azi, off, 64);
        s_ae  += __shfl_down(s_ae,  off, 64);
    }

    __shared__ float sm[4][5];
    __shared__ int   sm_last;
    __shared__ double dsm[4][5];

    const int wave = threadIdx.x >> 6;
    const int lane = threadIdx.x & 63;
    if (lane == 0) {
        sm[wave][0] = act;  sm[wave][1] = corr; sm[wave][2] = s_ele;
        sm[wave][3] = s_azi; sm[wave][4] = s_ae;
    }
    __syncthreads();
    if (threadIdx.x == 0) {
        part[0 * NBLK + blockIdx.x] = sm[0][0] + sm[1][0] + sm[2][0] + sm[3][0];
        part[1 * NBLK + blockIdx.x] = sm[0][1] + sm[1][1] + sm[2][1] + sm[3][1];
        part[2 * NBLK + blockIdx.x] = sm[0][2] + sm[1][2] + sm[2][2] + sm[3][2];
        part[3 * NBLK + blockIdx.x] = sm[0][3] + sm[1][3] + sm[2][3] + sm[3][3];
        part[4 * NBLK + blockIdx.x] = sm[0][4] + sm[1][4] + sm[2][4] + sm[3][4];
        // release: make partials visible device-wide before signalling arrival
        __threadfence();
        unsigned old = atomicAdd(cnt, 1u);
        sm_last = (old == (unsigned)(NBLK - 1)) ? 1 : 0;
    }
    __syncthreads();
    if (!sm_last) return;

    // ---- last-arriving block: finalize (identical order/precision to the old
    // metric_finalize kernel → bit-identical outputs) ----
    __threadfence();   // acquire: see every block's partials
    const int t = threadIdx.x;
    double v[5];
#pragma unroll
    for (int m = 0; m < 5; ++m) {
        double acc = 0.0;
#pragma unroll
        for (int j = 0; j < NBLK / NTHR; ++j)
            acc += (double)part[m * NBLK + j * NTHR + t];
        v[m] = acc;
    }
#pragma unroll
    for (int off = 32; off > 0; off >>= 1)
#pragma unroll
        for (int m = 0; m < 5; ++m)
            v[m] += __shfl_down(v[m], off, 64);

    if (lane == 0)
#pragma unroll
        for (int m = 0; m < 5; ++m) dsm[wave][m] = v[m];
    __syncthreads();
    if (t == 0) {
        double tot[5];
#pragma unroll
        for (int m = 0; m < 5; ++m)
            tot[m] = dsm[0][m] + dsm[1][m] + dsm[2][m] + dsm[3][m];
        double act_s = tot[0];
        out[0] = (float)(tot[1] / act_s);   // ACC
        out[1] = (float)(tot[2] / act_s);   // MAE ele
        out[2] = (float)(tot[3] / act_s);   // MAE azi
        out[3] = (float)(tot[4] / act_s);   // MAE aziele
    }
}

} // namespace

extern "C" void kernel_launch(void* const* d_in, const int* in_sizes, int n_in,
                              void* d_out, int out_size, void* d_ws, size_t ws_size,
                              hipStream_t stream) {
    const float* doa_gt  = (const float*)d_in[0];
    const float* vad_gt  = (const float*)d_in[1];
    const float* doa_est = (const float*)d_in[2];
    const float* vad_est = (const float*)d_in[3];
    float* part = (float*)d_ws;                                  // 5 * NBLK floats = 40 KB
    unsigned* cnt = (unsigned*)((char*)d_ws + 5 * NBLK * sizeof(float));
    float* out  = (float*)d_out;

    // Arrival counter must be 0 at every launch (graph replays included) —
    // a 4-byte memset node is graph-capturable and ~free.
    hipMemsetAsync(cnt, 0, sizeof(unsigned), stream);
    metric_main<<<NBLK, NTHR, 0, stream>>>(doa_gt, vad_gt, doa_est, vad_est, part, cnt, out);
}

// Round 3
// 118.576 us; speedup vs baseline: 1.8574x; 1.7880x over previous
//
#include <hip/hip_runtime.h>
#include <math.h>

namespace {

constexpr int NB = 64, NT = 16384;
constexpr int NBT = NB * NT;              // 1,048,576 (b,t) pairs, 4 sources each
constexpr int NBLK   = 2048;              // blocks in main kernel
constexpr int NTHR   = 256;
constexpr int NPASS  = NBT / (NBLK * NTHR);   // 2 pairs per thread
constexpr float VAD_TH  = 2.0f / 3.0f;
constexpr float AE_TH   = 30.0f;
constexpr float D2R     = 0.017453292519943295f;
constexpr float R2D     = 57.29577951308232f;
constexpr float CLIPV   = 0.99999f;

// ws layout: float part[5][NBLK]  (SoA). metrics: 0=act 1=corr 2=ele 3=azi 4=aziele
//
// SESSION NOTES (keep!):
//  * Round 1: __builtin_nontemporal_load on the input streams → 121 µs main at
//    438 GB/s. nt bypasses L2/L3; inputs partially L3-resident (FETCH_SIZE
//    ~50% of input bytes with plain loads). Plain float4 loads are correct.
//  * Rounds 1-2: fusing finalize into metric_main via per-block
//    __threadfence() + contended atomicAdd counter → main ballooned to
//    ~118 µs even with ZERO hbm traffic in the replay pass (ords 151/159:
//    3.6 GB/s, still 109 µs). On 8 non-coherent XCDs, the per-block release
//    fence (L2 writeback) + 2048 serialized far atomics cost ~110 µs —
//    20× the ~5 µs finalize launch they save. Keep the two-kernel split.

__device__ __forceinline__ void process4(
    const float4& eg, const float4& ag, const float4& ee, const float4& ae,
    const float4& vg4, const float4& ve4,
    float& act, float& corr, float& s_ele, float& s_azi, float& s_ae)
{
    float egA[4] = {eg.x, eg.y, eg.z, eg.w}, agA[4] = {ag.x, ag.y, ag.z, ag.w};
    float eeA[4] = {ee.x, ee.y, ee.z, ee.w}, aeA[4] = {ae.x, ae.y, ae.z, ae.w};
    float vgA[4] = {vg4.x, vg4.y, vg4.z, vg4.w}, veA[4] = {ve4.x, ve4.y, ve4.z, ve4.w};

#pragma unroll
    for (int s = 0; s < 4; ++s) {
        float vg = (vgA[s] > VAD_TH) ? 1.f : 0.f;
        float ve = (veA[s] > VAD_TH) ? vg : 0.f;

        // floor-mod(d,360) for d in [-180,540]; bit-identical to numpy's
        // fmod-then-adjust (Sterbenz for the subtract branch).
        float d = aeA[s] - agA[s] + 180.f;
        d = (d < 0.f) ? d + 360.f : d;
        d = (d >= 360.f) ? d - 360.f : d;
        float azi_err = fabsf(d - 180.f);

        float ele_err = fabsf(eeA[s] - egA[s]);

        float gr = egA[s] * D2R;
        float er = eeA[s] * D2R;
        float ar = agA[s] * D2R - aeA[s] * D2R;
        float aux = __cosf(gr) * __cosf(er) + __sinf(gr) * __sinf(er) * __cosf(ar);
        aux = fminf(fmaxf(aux, -CLIPV), CLIPV);
        float ae_err = acosf(aux) * R2D;     // acos >= 0

        act += vg;
        if (azi_err < AE_TH) corr += ve;
        s_ele += vg * ele_err;
        s_azi += vg * azi_err;
        s_ae  += vg * ae_err;
    }
}

__global__ __launch_bounds__(NTHR) void metric_main(
    const float* __restrict__ doa_gt, const float* __restrict__ vad_gt,
    const float* __restrict__ doa_est, const float* __restrict__ vad_est,
    float* __restrict__ part)
{
    const int gid = blockIdx.x * NTHR + threadIdx.x;

    const float4* dg = reinterpret_cast<const float4*>(doa_gt);
    const float4* de = reinterpret_cast<const float4*>(doa_est);
    const float4* vg_p = reinterpret_cast<const float4*>(vad_gt);
    const float4* ve_p = reinterpret_cast<const float4*>(vad_est);

    // Issue ALL loads before any compute: 12 outstanding float4 loads/thread
    // (memory-level parallelism — the loop is latency-bound when passes
    // serialize their loads).
    const int i0 = gid;                       // pass 0, coalesced
    const int i1 = gid + NBLK * NTHR;         // pass 1, coalesced
    static_assert(NPASS == 2, "load schedule assumes 2 passes");

    float4 eg0 = dg[2 * i0], ag0 = dg[2 * i0 + 1];
    float4 ee0 = de[2 * i0], ae0 = de[2 * i0 + 1];
    float4 eg1 = dg[2 * i1], ag1 = dg[2 * i1 + 1];
    float4 ee1 = de[2 * i1], ae1 = de[2 * i1 + 1];
    float4 vg40 = vg_p[i0], ve40 = ve_p[i0];
    float4 vg41 = vg_p[i1], ve41 = ve_p[i1];

    float act = 0.f, corr = 0.f, s_ele = 0.f, s_azi = 0.f, s_ae = 0.f;
    process4(eg0, ag0, ee0, ae0, vg40, ve40, act, corr, s_ele, s_azi, s_ae);
    process4(eg1, ag1, ee1, ae1, vg41, ve41, act, corr, s_ele, s_azi, s_ae);

    // wave64 shuffle reduction
#pragma unroll
    for (int off = 32; off > 0; off >>= 1) {
        act   += __shfl_down(act,   off, 64);
        corr  += __shfl_down(corr,  off, 64);
        s_ele += __shfl_down(s_ele, off, 64);
        s_azi += __shfl_down(s_azi, off, 64);
        s_ae  += __shfl_down(s_ae,  off, 64);
    }

    __shared__ float sm[4][5];
    const int wave = threadIdx.x >> 6;
    const int lane = threadIdx.x & 63;
    if (lane == 0) {
        sm[wave][0] = act;  sm[wave][1] = corr; sm[wave][2] = s_ele;
        sm[wave][3] = s_azi; sm[wave][4] = s_ae;
    }
    __syncthreads();
    if (threadIdx.x == 0) {
        part[0 * NBLK + blockIdx.x] = sm[0][0] + sm[1][0] + sm[2][0] + sm[3][0];
        part[1 * NBLK + blockIdx.x] = sm[0][1] + sm[1][1] + sm[2][1] + sm[3][1];
        part[2 * NBLK + blockIdx.x] = sm[0][2] + sm[1][2] + sm[2][2] + sm[3][2];
        part[3 * NBLK + blockIdx.x] = sm[0][3] + sm[1][3] + sm[2][3] + sm[3][3];
        part[4 * NBLK + blockIdx.x] = sm[0][4] + sm[1][4] + sm[2][4] + sm[3][4];
    }
}

// One block: reduce 5 x NBLK partials in double, write 4 outputs.
__global__ __launch_bounds__(NTHR) void metric_finalize(
    const float* __restrict__ part, float* __restrict__ out)
{
    __shared__ double dsm[4][5];
    const int t = threadIdx.x;
    double v[5];
#pragma unroll
    for (int m = 0; m < 5; ++m) {
        double acc = 0.0;
#pragma unroll
        for (int j = 0; j < NBLK / NTHR; ++j)
            acc += (double)part[m * NBLK + j * NTHR + t];
        v[m] = acc;
    }
#pragma unroll
    for (int off = 32; off > 0; off >>= 1)
#pragma unroll
        for (int m = 0; m < 5; ++m)
            v[m] += __shfl_down(v[m], off, 64);

    const int wave = t >> 6, lane = t & 63;
    if (lane == 0)
#pragma unroll
        for (int m = 0; m < 5; ++m) dsm[wave][m] = v[m];
    __syncthreads();
    if (t == 0) {
        double tot[5];
#pragma unroll
        for (int m = 0; m < 5; ++m)
            tot[m] = dsm[0][m] + dsm[1][m] + dsm[2][m] + dsm[3][m];
        double act = tot[0];
        out[0] = (float)(tot[1] / act);   // ACC
        out[1] = (float)(tot[2] / act);   // MAE ele
        out[2] = (float)(tot[3] / act);   // MAE azi
        out[3] = (float)(tot[4] / act);   // MAE aziele
    }
}

} // namespace

extern "C" void kernel_launch(void* const* d_in, const int* in_sizes, int n_in,
                              void* d_out, int out_size, void* d_ws, size_t ws_size,
                              hipStream_t stream) {
    const float* doa_gt  = (const float*)d_in[0];
    const float* vad_gt  = (const float*)d_in[1];
    const float* doa_est = (const float*)d_in[2];
    const float* vad_est = (const float*)d_in[3];
    float* part = (float*)d_ws;          // 5 * NBLK floats = 40 KB
    float* out  = (float*)d_out;

    metric_main<<<NBLK, NTHR, 0, stream>>>(doa_gt, vad_gt, doa_est, vad_est, part);
    metric_finalize<<<1, NTHR, 0, stream>>>(part, out);
}